// Round 3
// baseline (186.961 us; speedup 1.0000x reference)
//
#include <hip/hip_runtime.h>
#include <stdint.h>

// Problem constants (from reference)
#define N_NODES 50000
#define DEG     32
#define IN_DIM  256
#define K1      512   // 2*IN_DIM
#define HID     256
#define OUT_DIM 128

// fp8 gather tiling
#define NCHUNK  4
#define CDIM    64                          // dims per chunk (64 B fp8 per node-chunk)
#define SLICE8  ((size_t)N_NODES * CDIM)    // bytes per chunk slice (3.2 MB)
#define GT      64                          // nodes per gather block (64 slots x 4 quarters = 256 thr)
#define SIDXSTR 40                          // sIdx row stride in u16 (80 B: 16B-aligned, bank-spread)

// GEMM tiling
#define MT     32                           // nodes per tile
#define NTILES ((N_NODES + MT - 1) / MT)    // 1563
#define GBLK   256                          // persistent blocks (1/CU)
#define CSTR   520    // combined LDS row stride, bf16 elems (1040 B; row data 1024 B + 16 B pad)
#define HSTR   264    // h LDS row stride, bf16 elems (528 B)

typedef __bf16 bf16x8 __attribute__((ext_vector_type(8)));
typedef float  f32x4  __attribute__((ext_vector_type(4)));
typedef float  f32x2  __attribute__((ext_vector_type(2)));
typedef unsigned short u16x8 __attribute__((ext_vector_type(8)));
typedef unsigned int   u32x4 __attribute__((ext_vector_type(4)));

#define PIN(x) asm volatile("" : "+v"(x))

__device__ __forceinline__ unsigned short f2bf(float f) {
    union { float f; unsigned u; } v; v.f = f;
    unsigned r = v.u + 0x7fffu + ((v.u >> 16) & 1u);  // RNE (inputs finite)
    return (unsigned short)(r >> 16);
}
__device__ __forceinline__ int clampN(int v) {
    return v < 0 ? 0 : (v >= N_NODES ? N_NODES - 1 : v);
}
__device__ __forceinline__ void async_copy16(const void* g, void* l) {
    __builtin_amdgcn_global_load_lds(
        (const __attribute__((address_space(1))) void*)g,
        (__attribute__((address_space(3))) void*)l, 16, 0, 0);
}

// ---------------- merged prep: feat->bf16 + fp8 tiled; W1/W2->bf16; nbr->u16 ----------------
#define FEAT_BLKS ((N_NODES + 7) / 8)   // 6250
__global__ __launch_bounds__(256)
void prep_all(const float* __restrict__ feat,
              const float* __restrict__ W1, const float* __restrict__ W2,
              const int*   __restrict__ nbr,
              unsigned short* __restrict__ featb,   // [N,256] bf16
              unsigned char*  __restrict__ featF8,  // [4][N][64] fp8 e4m3
              unsigned short* __restrict__ W1b, unsigned short* __restrict__ W2b,
              unsigned short* __restrict__ nbr16)
{
    const int t = threadIdx.x;
    if (blockIdx.x < FEAT_BLKS) {
        const int node = blockIdx.x * 8 + (t >> 5);  // 8 nodes/block
        const int seg  = t & 31;                     // dims seg*8 .. seg*8+7
        if (node < N_NODES) {
            const float4* src = (const float4*)(feat + (size_t)node * IN_DIM + seg * 8);
            float4 f0 = src[0], f1 = src[1];
            ushort4 o0, o1;
            o0.x = f2bf(f0.x); o0.y = f2bf(f0.y); o0.z = f2bf(f0.z); o0.w = f2bf(f0.w);
            o1.x = f2bf(f1.x); o1.y = f2bf(f1.y); o1.z = f2bf(f1.z); o1.w = f2bf(f1.w);
            unsigned short* db = featb + (size_t)node * IN_DIM + seg * 8;
            *(ushort4*)db       = o0;
            *(ushort4*)(db + 4) = o1;
            int u0 = 0, u1 = 0;
            u0 = __builtin_amdgcn_cvt_pk_fp8_f32(f0.x, f0.y, u0, false);
            u0 = __builtin_amdgcn_cvt_pk_fp8_f32(f0.z, f0.w, u0, true);
            u1 = __builtin_amdgcn_cvt_pk_fp8_f32(f1.x, f1.y, u1, false);
            u1 = __builtin_amdgcn_cvt_pk_fp8_f32(f1.z, f1.w, u1, true);
            const int c   = seg >> 3;
            const int off = (seg & 7) * 8;
            unsigned char* d8 = featF8 + (size_t)c * SLICE8 + (size_t)node * CDIM + off;
            ((int*)d8)[0] = u0;
            ((int*)d8)[1] = u1;
        }
    } else {
        const int bid = blockIdx.x - FEAT_BLKS;           // 0..255
        const int stride = 256 * 256 * 4;
        const int tid4 = (bid * 256 + t) * 4;
        for (int i = tid4; i < HID * K1; i += stride) {
            float4 f = *(const float4*)(W1 + i);
            ushort4 o; o.x = f2bf(f.x); o.y = f2bf(f.y); o.z = f2bf(f.z); o.w = f2bf(f.w);
            *(ushort4*)(W1b + i) = o;
        }
        for (int i = tid4; i < OUT_DIM * HID; i += stride) {
            float4 f = *(const float4*)(W2 + i);
            ushort4 o; o.x = f2bf(f.x); o.y = f2bf(f.y); o.z = f2bf(f.z); o.w = f2bf(f.w);
            *(ushort4*)(W2b + i) = o;
        }
        for (int i = tid4; i < N_NODES * DEG; i += stride) {
            int4 v = *(const int4*)(nbr + i);
            ushort4 o;
            o.x = (unsigned short)clampN(v.x); o.y = (unsigned short)clampN(v.y);
            o.z = (unsigned short)clampN(v.z); o.w = (unsigned short)clampN(v.w);
            *(ushort4*)(nbr16 + i) = o;
        }
    }
}

// ---------------- gather + mean: fp8 slices, 16B/lane, software-pipelined batches ----------------
// thread = (node-slot grp 0..63, 16B-quarter gl 0..3); block covers 64 nodes of one chunk.
// Two 8-deep register buffers: batch b+1's loads are issued BEFORE batch b's converts,
// so a wave never drains vmcnt to 0 in the steady state (compiler emits vmcnt(8) waits).
// FP summation order per output dim identical to rounds 0/2 (j = 0..31 sequential).
__global__ __launch_bounds__(256, 4)
void gather_mean_fp8(const unsigned char*  __restrict__ featF8,
                     const unsigned short* __restrict__ nbr16,
                     unsigned short*       __restrict__ meanb)  // [N,256] bf16
{
    __shared__ __align__(16) unsigned short sIdx[GT * SIDXSTR];  // 5 KB (padded rows)
    const int tid  = threadIdx.x;
    const int c    = blockIdx.y;
    const int base = blockIdx.x * GT;

    // stage indices: thread t -> row (t&63), 8-elem segment (t>>6)
    {
        const int row = tid & 63;
        const int seg = tid >> 6;           // 0..3
        const int node = base + row;
        if (node < N_NODES) {
            *(u16x8*)(sIdx + row * SIDXSTR + seg * 8) =
                *(const u16x8*)(nbr16 + (size_t)node * DEG + seg * 8);
        }
    }
    __syncthreads();

    const int grp = tid >> 2;     // node slot 0..63
    const int gl  = tid & 3;      // 16B quarter of the 64B chunk row
    const int node = base + grp;
    if (node >= N_NODES) return;

    const unsigned char*  sl = featF8 + (size_t)c * SLICE8 + gl * 16;
    const unsigned short* ip = sIdx + grp * SIDXSTR;

    const u16x8 id0 = *(const u16x8*)(ip);
    const u16x8 id1 = *(const u16x8*)(ip + 8);
    const u16x8 id2 = *(const u16x8*)(ip + 16);
    const u16x8 id3 = *(const u16x8*)(ip + 24);

    f32x2 ga[8];
    #pragma unroll
    for (int k = 0; k < 8; ++k) ga[k] = (f32x2){0.f, 0.f};

    auto acc8 = [&](const u32x4* V) {
        #pragma unroll
        for (int j = 0; j < 8; ++j) {
            #pragma unroll
            for (int w = 0; w < 4; ++w) {
                f32x2 lo = __builtin_amdgcn_cvt_pk_f32_fp8(V[j][w], false);
                f32x2 hi = __builtin_amdgcn_cvt_pk_f32_fp8(V[j][w], true);
                ga[w * 2]     += lo;
                ga[w * 2 + 1] += hi;
            }
        }
    };

    u32x4 vA[8], vB[8];
    #pragma unroll
    for (int j = 0; j < 8; ++j) vA[j] = *(const u32x4*)(sl + (size_t)id0[j] * CDIM);
    #pragma unroll
    for (int j = 0; j < 8; ++j) vB[j] = *(const u32x4*)(sl + (size_t)id1[j] * CDIM);
    acc8(vA);                                             // batch 0 (batch 1 in flight)
    #pragma unroll
    for (int j = 0; j < 8; ++j) vA[j] = *(const u32x4*)(sl + (size_t)id2[j] * CDIM);
    acc8(vB);                                             // batch 1 (batch 2 in flight)
    #pragma unroll
    for (int j = 0; j < 8; ++j) vB[j] = *(const u32x4*)(sl + (size_t)id3[j] * CDIM);
    acc8(vA);                                             // batch 2 (batch 3 in flight)
    acc8(vB);                                             // batch 3

    const float sc = 1.0f / 32.0f;
    u32x4 p0, p1;
    #pragma unroll
    for (int k = 0; k < 4; ++k) {
        p0[k] = (unsigned)f2bf(ga[k][0] * sc)     | ((unsigned)f2bf(ga[k][1] * sc) << 16);
        p1[k] = (unsigned)f2bf(ga[4 + k][0] * sc) | ((unsigned)f2bf(ga[4 + k][1] * sc) << 16);
    }
    unsigned short* dst = meanb + (size_t)node * IN_DIM + c * CDIM + gl * 16;
    *(u32x4*)dst       = p0;   // dims +0..7
    *(u32x4*)(dst + 8) = p1;   // dims +8..15
}

// ---------------- persistent GEMM: dbuf async staging + pinned W fragments ----------------
// MFMA fragment layouts (measured, learn_hip m89/m91/m120):
//   A operand: lane holds A[m = lane&15][k = (lane>>4)*8 + j], j=0..7
//   B operand (W row-major [n][k]): lane holds W[n = lane&15][k = (lane>>4)*8 + j]
//   C/D: col(n) = lane&15, row(m) = (lane>>4)*4 + reg
__global__ __launch_bounds__(512, 2)
void sage_gemm_dbuf(const unsigned short* __restrict__ featb,  // [N,256] bf16
                    const unsigned short* __restrict__ meanb,  // [N,256] bf16
                    const unsigned short* __restrict__ W1b,    // [256,512] bf16
                    const float*          __restrict__ b1,
                    const unsigned short* __restrict__ W2b,    // [128,256] bf16
                    const float*          __restrict__ b2,
                    float*                __restrict__ out)    // [N,128]
{
    __shared__ __align__(16) unsigned short sC[2][MT * CSTR];  // 2 x 33280 B
    __shared__ __align__(16) unsigned short sH[MT * HSTR];     // 16896 B (83456 total)

    const int tid  = threadIdx.x;
    const int lane = tid & 63;
    const int wave = tid >> 6;     // 0..7
    const int r    = lane & 15;
    const int q    = lane >> 4;

    // ---- one-time: W fragments into registers, pinned against remat ----
    bf16x8 w1f[2][16];   // h-cols wave*32 + nt*16 + r
    #pragma unroll
    for (int nt = 0; nt < 2; ++nt) {
        const size_t nrow = (size_t)(wave * 32 + nt * 16 + r) * K1;
        #pragma unroll
        for (int kk = 0; kk < 16; ++kk) {
            w1f[nt][kk] = *(const bf16x8*)(W1b + nrow + kk * 32 + q * 8);
            PIN(w1f[nt][kk]);
        }
    }
    bf16x8 w2f[8];       // out-col wave*16 + r
    {
        const size_t orow = (size_t)(wave * 16 + r) * HID;
        #pragma unroll
        for (int kk = 0; kk < 8; ++kk) {
            w2f[kk] = *(const bf16x8*)(W2b + orow + kk * 32 + q * 8);
            PIN(w2f[kk]);
        }
    }
    const float bias1a = b1[wave * 32 + r];
    const float bias1b = b1[wave * 32 + 16 + r];
    const float bias2  = b2[wave * 16 + r];

    // per-lane source offset within a combined row (self 512B | mean 512B)
    // HW writes lane i at lds_base + i*16 -> exactly our row layout.
    auto stage = [&](int tile, int buf) {
        const int base = tile * MT;
        #pragma unroll
        for (int j = 0; j < 4; ++j) {
            const int i = wave * 4 + j;           // row 0..31 (wave-uniform)
            int node = base + i;
            if (node >= N_NODES) node = N_NODES - 1;
            const unsigned short* g = (lane < 32)
                ? featb + (size_t)node * IN_DIM + lane * 8
                : meanb + (size_t)node * IN_DIM + (lane - 32) * 8;
            async_copy16(g, &sC[buf][i * CSTR]);
        }
    };

    int tile = blockIdx.x;
    if (tile < NTILES) stage(tile, 0);
    int buf = 0;

    for (; tile < NTILES; tile += GBLK) {
        __syncthreads();   // compiler drains vmcnt before s_barrier: sC[buf] ready

        const int nxt = tile + GBLK;
        if (nxt < NTILES) stage(nxt, buf ^ 1);   // overlaps phase 2

        // ---- Phase 2: h = relu(C @ W1^T + b1); wave covers h-cols [wave*32, +32) ----
        {
            f32x4 acc[2][2];
            #pragma unroll
            for (int mt = 0; mt < 2; ++mt)
                #pragma unroll
                for (int nt = 0; nt < 2; ++nt)
                    acc[mt][nt] = (f32x4){0.f, 0.f, 0.f, 0.f};

            #pragma unroll
            for (int kk = 0; kk < 16; ++kk) {
                bf16x8 a0 = *(const bf16x8*)(&sC[buf][r * CSTR + kk * 32 + q * 8]);
                bf16x8 a1 = *(const bf16x8*)(&sC[buf][(16 + r) * CSTR + kk * 32 + q * 8]);
                acc[0][0] = __builtin_amdgcn_mfma_f32_16x16x32_bf16(a0, w1f[0][kk], acc[0][0], 0, 0, 0);
                acc[1][0] = __builtin_amdgcn_mfma_f32_16x16x32_bf16(a1, w1f[0][kk], acc[1][0], 0, 0, 0);
                acc[0][1] = __builtin_amdgcn_mfma_f32_16x16x32_bf16(a0, w1f[1][kk], acc[0][1], 0, 0, 0);
                acc[1][1] = __builtin_amdgcn_mfma_f32_16x16x32_bf16(a1, w1f[1][kk], acc[1][1], 0, 0, 0);
            }
            #pragma unroll
            for (int nt = 0; nt < 2; ++nt) {
                const int n = wave * 32 + nt * 16 + r;
                const float bias = nt ? bias1b : bias1a;
                #pragma unroll
                for (int mt = 0; mt < 2; ++mt)
                    #pragma unroll
                    for (int g = 0; g < 4; ++g) {
                        const int m = mt * 16 + q * 4 + g;
                        float v = acc[mt][nt][g] + bias;
                        sH[m * HSTR + n] = f2bf(v > 0.f ? v : 0.f);
                    }
            }
        }
        __syncthreads();   // sH ready (also drains the prefetch early — accepted)

        // ---- Phase 3: out = relu(h @ W2^T + b2); wave covers out-cols [wave*16, +16) ----
        {
            f32x4 acc3[2];
            acc3[0] = (f32x4){0.f, 0.f, 0.f, 0.f};
            acc3[1] = (f32x4){0.f, 0.f, 0.f, 0.f};
            #pragma unroll
            for (int kk = 0; kk < 8; ++kk) {
                bf16x8 h0 = *(const bf16x8*)(&sH[r * HSTR + kk * 32 + q * 8]);
                bf16x8 h1 = *(const bf16x8*)(&sH[(16 + r) * HSTR + kk * 32 + q * 8]);
                acc3[0] = __builtin_amdgcn_mfma_f32_16x16x32_bf16(h0, w2f[kk], acc3[0], 0, 0, 0);
                acc3[1] = __builtin_amdgcn_mfma_f32_16x16x32_bf16(h1, w2f[kk], acc3[1], 0, 0, 0);
            }
            const int base = tile * MT;
            const int o = wave * 16 + r;
            #pragma unroll
            for (int mt = 0; mt < 2; ++mt)
                #pragma unroll
                for (int g = 0; g < 4; ++g) {
                    const int m = mt * 16 + q * 4 + g;
                    const int node = base + m;
                    if (node < N_NODES) {
                        float v = acc3[mt][g] + bias2;
                        out[(size_t)node * OUT_DIM + o] = v > 0.f ? v : 0.f;
                    }
                }
        }
        buf ^= 1;
    }
}

// ---------------- naive fp32 fallback (only if ws too small) ----------------
__global__ __launch_bounds__(256)
void sage_naive(const float* __restrict__ feat, const int* __restrict__ nbr,
                const float* __restrict__ W1, const float* __restrict__ b1,
                const float* __restrict__ W2, const float* __restrict__ b2,
                float* __restrict__ out) {
    __shared__ float comb[K1];
    __shared__ float h[HID];
    const int node = blockIdx.x;
    const int t = threadIdx.x;  // 256
    comb[t] = feat[(size_t)node * IN_DIM + t];
    float acc = 0.f;
    for (int d = 0; d < DEG; ++d) {
        int nb = clampN(nbr[node * DEG + d]);
        acc += feat[(size_t)nb * IN_DIM + t];
    }
    comb[IN_DIM + t] = acc * (1.0f / 32.0f);
    __syncthreads();
    float s = b1[t];
    for (int k = 0; k < K1; ++k) s += comb[k] * W1[(size_t)t * K1 + k];
    h[t] = s > 0.f ? s : 0.f;
    __syncthreads();
    if (t < OUT_DIM) {
        float s2 = b2[t];
        for (int k = 0; k < HID; ++k) s2 += h[k] * W2[(size_t)t * HID + k];
        out[(size_t)node * OUT_DIM + t] = s2 > 0.f ? s2 : 0.f;
    }
}

extern "C" void kernel_launch(void* const* d_in, const int* in_sizes, int n_in,
                              void* d_out, int out_size, void* d_ws, size_t ws_size,
                              hipStream_t stream) {
    const float* feat = (const float*)d_in[0];
    const int*   nbr  = (const int*)d_in[1];
    const float* W1   = (const float*)d_in[2];
    const float* b1   = (const float*)d_in[3];
    const float* W2   = (const float*)d_in[4];
    const float* b2   = (const float*)d_in[5];
    float* out = (float*)d_out;

    const size_t feat_elems = (size_t)N_NODES * IN_DIM;   // 12.8M
    const size_t w1_elems   = (size_t)HID * K1;
    const size_t w2_elems   = (size_t)OUT_DIM * HID;
    const size_t mean_elems = (size_t)N_NODES * IN_DIM;
    const size_t idx_elems  = (size_t)N_NODES * DEG;
    const size_t u16_elems  = feat_elems + w1_elems + w2_elems + mean_elems + idx_elems;
    const size_t need = u16_elems * sizeof(unsigned short)
                      + (size_t)NCHUNK * SLICE8;          // ~67.6 MB

    if (ws_size >= need) {
        unsigned short* featb  = (unsigned short*)d_ws;
        unsigned short* W1b    = featb + feat_elems;
        unsigned short* W2b    = W1b + w1_elems;
        unsigned short* meanb  = W2b + w2_elems;
        unsigned short* nbr16  = meanb + mean_elems;
        unsigned char*  featF8 = (unsigned char*)(nbr16 + idx_elems);

        prep_all<<<FEAT_BLKS + 256, 256, 0, stream>>>(feat, W1, W2, nbr,
                                                      featb, featF8, W1b, W2b, nbr16);
        gather_mean_fp8<<<dim3((N_NODES + GT - 1) / GT, NCHUNK), 256, 0, stream>>>(featF8, nbr16, meanb);
        sage_gemm_dbuf<<<GBLK, 512, 0, stream>>>(featb, meanb, W1b, b1, W2b, b2, out);
    } else {
        sage_naive<<<N_NODES, 256, 0, stream>>>(feat, nbr, W1, b1, W2, b2, out);
    }
}

// Round 4
// 181.194 us; speedup vs baseline: 1.0318x; 1.0318x over previous
//
#include <hip/hip_runtime.h>
#include <stdint.h>

// Problem constants (from reference)
#define N_NODES 50000
#define DEG     32
#define IN_DIM  256
#define K1      512   // 2*IN_DIM
#define HID     256
#define OUT_DIM 128

// fp8 gather tiling
#define NCHUNK  4
#define CDIM    64                          // dims per chunk (64 B fp8 per node-chunk)
#define SLICE8  ((size_t)N_NODES * CDIM)    // bytes per chunk slice (3.2 MB)
#define GT      16                          // nodes per gather block

// GEMM tiling
#define MT     32                           // nodes per tile
#define NTILES ((N_NODES + MT - 1) / MT)    // 1563
#define GBLK   512                          // persistent blocks (2/CU if LDS/VGPR allow)
#define CSTR   520    // combined LDS row stride, bf16 elems (1040 B; row data 1024 B + 16 B pad)
#define HSTR   264    // h LDS row stride, bf16 elems (528 B)

typedef __bf16 bf16x8 __attribute__((ext_vector_type(8)));
typedef float  f32x4  __attribute__((ext_vector_type(4)));
typedef float  f32x2  __attribute__((ext_vector_type(2)));

#define PIN(x) asm volatile("" : "+v"(x))

__device__ __forceinline__ unsigned short f2bf(float f) {
    union { float f; unsigned u; } v; v.f = f;
    unsigned r = v.u + 0x7fffu + ((v.u >> 16) & 1u);  // RNE (inputs finite)
    return (unsigned short)(r >> 16);
}
__device__ __forceinline__ int clampN(int v) {
    return v < 0 ? 0 : (v >= N_NODES ? N_NODES - 1 : v);
}
__device__ __forceinline__ void async_copy16(const void* g, void* l) {
    __builtin_amdgcn_global_load_lds(
        (const __attribute__((address_space(1))) void*)g,
        (__attribute__((address_space(3))) void*)l, 16, 0, 0);
}

// ---------------- merged prep: feat->bf16 + fp8 tiled; W1/W2->bf16; nbr->u16 ----------------
#define FEAT_BLKS ((N_NODES + 7) / 8)   // 6250
__global__ __launch_bounds__(256)
void prep_all(const float* __restrict__ feat,
              const float* __restrict__ W1, const float* __restrict__ W2,
              const int*   __restrict__ nbr,
              unsigned short* __restrict__ featb,   // [N,256] bf16
              unsigned char*  __restrict__ featF8,  // [4][N][64] fp8 e4m3
              unsigned short* __restrict__ W1b, unsigned short* __restrict__ W2b,
              unsigned short* __restrict__ nbr16)
{
    const int t = threadIdx.x;
    if (blockIdx.x < FEAT_BLKS) {
        const int node = blockIdx.x * 8 + (t >> 5);  // 8 nodes/block
        const int seg  = t & 31;                     // dims seg*8 .. seg*8+7
        if (node < N_NODES) {
            const float4* src = (const float4*)(feat + (size_t)node * IN_DIM + seg * 8);
            float4 f0 = src[0], f1 = src[1];
            ushort4 o0, o1;
            o0.x = f2bf(f0.x); o0.y = f2bf(f0.y); o0.z = f2bf(f0.z); o0.w = f2bf(f0.w);
            o1.x = f2bf(f1.x); o1.y = f2bf(f1.y); o1.z = f2bf(f1.z); o1.w = f2bf(f1.w);
            unsigned short* db = featb + (size_t)node * IN_DIM + seg * 8;
            *(ushort4*)db       = o0;
            *(ushort4*)(db + 4) = o1;
            int u0 = 0, u1 = 0;
            u0 = __builtin_amdgcn_cvt_pk_fp8_f32(f0.x, f0.y, u0, false);
            u0 = __builtin_amdgcn_cvt_pk_fp8_f32(f0.z, f0.w, u0, true);
            u1 = __builtin_amdgcn_cvt_pk_fp8_f32(f1.x, f1.y, u1, false);
            u1 = __builtin_amdgcn_cvt_pk_fp8_f32(f1.z, f1.w, u1, true);
            const int c   = seg >> 3;
            const int off = (seg & 7) * 8;
            unsigned char* d8 = featF8 + (size_t)c * SLICE8 + (size_t)node * CDIM + off;
            ((int*)d8)[0] = u0;
            ((int*)d8)[1] = u1;
        }
    } else {
        const int bid = blockIdx.x - FEAT_BLKS;           // 0..255
        const int stride = 256 * 256 * 4;
        const int tid4 = (bid * 256 + t) * 4;
        for (int i = tid4; i < HID * K1; i += stride) {
            float4 f = *(const float4*)(W1 + i);
            ushort4 o; o.x = f2bf(f.x); o.y = f2bf(f.y); o.z = f2bf(f.z); o.w = f2bf(f.w);
            *(ushort4*)(W1b + i) = o;
        }
        for (int i = tid4; i < OUT_DIM * HID; i += stride) {
            float4 f = *(const float4*)(W2 + i);
            ushort4 o; o.x = f2bf(f.x); o.y = f2bf(f.y); o.z = f2bf(f.z); o.w = f2bf(f.w);
            *(ushort4*)(W2b + i) = o;
        }
        for (int i = tid4; i < N_NODES * DEG; i += stride) {
            int4 v = *(const int4*)(nbr + i);
            ushort4 o;
            o.x = (unsigned short)clampN(v.x); o.y = (unsigned short)clampN(v.y);
            o.z = (unsigned short)clampN(v.z); o.w = (unsigned short)clampN(v.w);
            *(ushort4*)(nbr16 + i) = o;
        }
    }
}

// ---------------- gather + mean: fp8 slices, round-0 proven shape ----------------
// thread = (node-slot grp 0..15, dword ln 0..15); 4 B/lane; all 32 loads issued
// before any convert (max MLP, single vmcnt drain). ~0.27 lines/cy/CU measured
// cap (random-miss throughput) — this shape is the fastest of 3 tried (39/44/47).
__global__ __launch_bounds__(256)
void gather_mean_fp8(const unsigned char*  __restrict__ featF8,
                     const unsigned short* __restrict__ nbr16,
                     unsigned short*       __restrict__ meanb)  // [N,256] bf16
{
    __shared__ unsigned short sIdx[GT * DEG];  // 1 KB
    const int tid  = threadIdx.x;
    const int c    = blockIdx.y;
    const int base = blockIdx.x * GT;          // N % GT == 0: no tail

    if (tid < 128) {
        *(ushort4*)(sIdx + tid * 4) =
            *(const ushort4*)(nbr16 + (size_t)base * DEG + tid * 4);
    }
    __syncthreads();

    const unsigned char* slice = featF8 + (size_t)c * SLICE8;
    const int grp = tid >> 4;     // node slot 0..15
    const int ln  = tid & 15;     // dims 4*ln .. 4*ln+3 of the chunk
    const unsigned short* idxr = sIdx + grp * DEG;

    // all 32 loads issued before any use: max memory-level parallelism
    unsigned vv[DEG];
    #pragma unroll
    for (int j = 0; j < DEG; ++j) {
        int nb = idxr[j];
        vv[j] = *(const unsigned*)(slice + (size_t)nb * CDIM + ln * 4);
    }
    float s0 = 0.f, s1 = 0.f, s2 = 0.f, s3 = 0.f;
    #pragma unroll
    for (int j = 0; j < DEG; ++j) {
        f32x2 lo = __builtin_amdgcn_cvt_pk_f32_fp8(vv[j], false);
        f32x2 hi = __builtin_amdgcn_cvt_pk_f32_fp8(vv[j], true);
        s0 += lo[0]; s1 += lo[1]; s2 += hi[0]; s3 += hi[1];
    }
    const float sc = 1.0f / 32.0f;
    ushort4 o;
    o.x = f2bf(s0 * sc); o.y = f2bf(s1 * sc);
    o.z = f2bf(s2 * sc); o.w = f2bf(s3 * sc);
    const int node = base + grp;
    *(ushort4*)(meanb + (size_t)node * IN_DIM + c * CDIM + ln * 4) = o;
}

// ---------------- persistent GEMM: single-buffer LDS (50 KB -> up to 3 blocks/CU) ----------------
// Round-1 evidence: fused variant allocated only 128 VGPR despite ~220 logical W-frag
// residency -> occupancy was LDS-bound, not VGPR-bound. Halve LDS (drop dbuf), keep
// cross-tile overlap by issuing stage(next) between phase 2 and phase 3 (vmcnt drains
// at the loop-top barrier, hidden under phase 3 + co-resident blocks).
// MFMA fragment layouts (measured, learn_hip m89/m91/m120):
//   A operand: lane holds A[m = lane&15][k = (lane>>4)*8 + j], j=0..7
//   B operand (W row-major [n][k]): lane holds W[n = lane&15][k = (lane>>4)*8 + j]
//   C/D: col(n) = lane&15, row(m) = (lane>>4)*4 + reg
__global__ __launch_bounds__(512, 2)
void sage_gemm(const unsigned short* __restrict__ featb,  // [N,256] bf16
               const unsigned short* __restrict__ meanb,  // [N,256] bf16
               const unsigned short* __restrict__ W1b,    // [256,512] bf16
               const float*          __restrict__ b1,
               const unsigned short* __restrict__ W2b,    // [128,256] bf16
               const float*          __restrict__ b2,
               float*                __restrict__ out)    // [N,128]
{
    __shared__ __align__(16) unsigned short sC[MT * CSTR];  // 33280 B
    __shared__ __align__(16) unsigned short sH[MT * HSTR];  // 16896 B (50176 total)

    const int tid  = threadIdx.x;
    const int lane = tid & 63;
    const int wave = tid >> 6;     // 0..7
    const int r    = lane & 15;
    const int q    = lane >> 4;

    // ---- one-time: W fragments into registers, pinned against remat ----
    bf16x8 w1f[2][16];   // h-cols wave*32 + nt*16 + r
    #pragma unroll
    for (int nt = 0; nt < 2; ++nt) {
        const size_t nrow = (size_t)(wave * 32 + nt * 16 + r) * K1;
        #pragma unroll
        for (int kk = 0; kk < 16; ++kk) {
            w1f[nt][kk] = *(const bf16x8*)(W1b + nrow + kk * 32 + q * 8);
            PIN(w1f[nt][kk]);
        }
    }
    bf16x8 w2f[8];       // out-col wave*16 + r
    {
        const size_t orow = (size_t)(wave * 16 + r) * HID;
        #pragma unroll
        for (int kk = 0; kk < 8; ++kk) {
            w2f[kk] = *(const bf16x8*)(W2b + orow + kk * 32 + q * 8);
            PIN(w2f[kk]);
        }
    }
    const float bias1a = b1[wave * 32 + r];
    const float bias1b = b1[wave * 32 + 16 + r];
    const float bias2  = b2[wave * 16 + r];

    // per-lane source offset within a combined row (self 512B | mean 512B)
    // HW writes lane i at lds_base + i*16 -> exactly our row layout.
    auto stage = [&](int tile) {
        const int base = tile * MT;
        #pragma unroll
        for (int j = 0; j < 4; ++j) {
            const int i = wave * 4 + j;           // row 0..31 (wave-uniform)
            int node = base + i;
            if (node >= N_NODES) node = N_NODES - 1;
            const unsigned short* g = (lane < 32)
                ? featb + (size_t)node * IN_DIM + lane * 8
                : meanb + (size_t)node * IN_DIM + (lane - 32) * 8;
            async_copy16(g, &sC[i * CSTR]);
        }
    };

    int tile = blockIdx.x;
    if (tile < NTILES) stage(tile);

    for (; tile < NTILES; tile += GBLK) {
        __syncthreads();   // compiler drains vmcnt before s_barrier: sC ready

        // ---- Phase 2: h = relu(C @ W1^T + b1); wave covers h-cols [wave*32, +32) ----
        {
            f32x4 acc[2][2];
            #pragma unroll
            for (int mt = 0; mt < 2; ++mt)
                #pragma unroll
                for (int nt = 0; nt < 2; ++nt)
                    acc[mt][nt] = (f32x4){0.f, 0.f, 0.f, 0.f};

            #pragma unroll
            for (int kk = 0; kk < 16; ++kk) {
                bf16x8 a0 = *(const bf16x8*)(&sC[r * CSTR + kk * 32 + q * 8]);
                bf16x8 a1 = *(const bf16x8*)(&sC[(16 + r) * CSTR + kk * 32 + q * 8]);
                acc[0][0] = __builtin_amdgcn_mfma_f32_16x16x32_bf16(a0, w1f[0][kk], acc[0][0], 0, 0, 0);
                acc[1][0] = __builtin_amdgcn_mfma_f32_16x16x32_bf16(a1, w1f[0][kk], acc[1][0], 0, 0, 0);
                acc[0][1] = __builtin_amdgcn_mfma_f32_16x16x32_bf16(a0, w1f[1][kk], acc[0][1], 0, 0, 0);
                acc[1][1] = __builtin_amdgcn_mfma_f32_16x16x32_bf16(a1, w1f[1][kk], acc[1][1], 0, 0, 0);
            }
            #pragma unroll
            for (int nt = 0; nt < 2; ++nt) {
                const int n = wave * 32 + nt * 16 + r;
                const float bias = nt ? bias1b : bias1a;
                #pragma unroll
                for (int mt = 0; mt < 2; ++mt)
                    #pragma unroll
                    for (int g = 0; g < 4; ++g) {
                        const int m = mt * 16 + q * 4 + g;
                        float v = acc[mt][nt][g] + bias;
                        sH[m * HSTR + n] = f2bf(v > 0.f ? v : 0.f);
                    }
            }
        }
        __syncthreads();   // sH ready; phase-2 reads of sC complete

        // ---- prefetch next tile into sC (overlaps phase 3; drains at loop-top barrier) ----
        const int nxt = tile + GBLK;
        if (nxt < NTILES) stage(nxt);

        // ---- Phase 3: out = relu(h @ W2^T + b2); wave covers out-cols [wave*16, +16) ----
        {
            f32x4 acc3[2];
            acc3[0] = (f32x4){0.f, 0.f, 0.f, 0.f};
            acc3[1] = (f32x4){0.f, 0.f, 0.f, 0.f};
            #pragma unroll
            for (int kk = 0; kk < 8; ++kk) {
                bf16x8 h0 = *(const bf16x8*)(&sH[r * HSTR + kk * 32 + q * 8]);
                bf16x8 h1 = *(const bf16x8*)(&sH[(16 + r) * HSTR + kk * 32 + q * 8]);
                acc3[0] = __builtin_amdgcn_mfma_f32_16x16x32_bf16(h0, w2f[kk], acc3[0], 0, 0, 0);
                acc3[1] = __builtin_amdgcn_mfma_f32_16x16x32_bf16(h1, w2f[kk], acc3[1], 0, 0, 0);
            }
            const int base = tile * MT;
            const int o = wave * 16 + r;
            #pragma unroll
            for (int mt = 0; mt < 2; ++mt)
                #pragma unroll
                for (int g = 0; g < 4; ++g) {
                    const int m = mt * 16 + q * 4 + g;
                    const int node = base + m;
                    if (node < N_NODES) {
                        float v = acc3[mt][g] + bias2;
                        out[(size_t)node * OUT_DIM + o] = v > 0.f ? v : 0.f;
                    }
                }
        }
    }
}

// ---------------- naive fp32 fallback (only if ws too small) ----------------
__global__ __launch_bounds__(256)
void sage_naive(const float* __restrict__ feat, const int* __restrict__ nbr,
                const float* __restrict__ W1, const float* __restrict__ b1,
                const float* __restrict__ W2, const float* __restrict__ b2,
                float* __restrict__ out) {
    __shared__ float comb[K1];
    __shared__ float h[HID];
    const int node = blockIdx.x;
    const int t = threadIdx.x;  // 256
    comb[t] = feat[(size_t)node * IN_DIM + t];
    float acc = 0.f;
    for (int d = 0; d < DEG; ++d) {
        int nb = clampN(nbr[node * DEG + d]);
        acc += feat[(size_t)nb * IN_DIM + t];
    }
    comb[IN_DIM + t] = acc * (1.0f / 32.0f);
    __syncthreads();
    float s = b1[t];
    for (int k = 0; k < K1; ++k) s += comb[k] * W1[(size_t)t * K1 + k];
    h[t] = s > 0.f ? s : 0.f;
    __syncthreads();
    if (t < OUT_DIM) {
        float s2 = b2[t];
        for (int k = 0; k < HID; ++k) s2 += h[k] * W2[(size_t)t * HID + k];
        out[(size_t)node * OUT_DIM + t] = s2 > 0.f ? s2 : 0.f;
    }
}

extern "C" void kernel_launch(void* const* d_in, const int* in_sizes, int n_in,
                              void* d_out, int out_size, void* d_ws, size_t ws_size,
                              hipStream_t stream) {
    const float* feat = (const float*)d_in[0];
    const int*   nbr  = (const int*)d_in[1];
    const float* W1   = (const float*)d_in[2];
    const float* b1   = (const float*)d_in[3];
    const float* W2   = (const float*)d_in[4];
    const float* b2   = (const float*)d_in[5];
    float* out = (float*)d_out;

    const size_t feat_elems = (size_t)N_NODES * IN_DIM;   // 12.8M
    const size_t w1_elems   = (size_t)HID * K1;
    const size_t w2_elems   = (size_t)OUT_DIM * HID;
    const size_t mean_elems = (size_t)N_NODES * IN_DIM;
    const size_t idx_elems  = (size_t)N_NODES * DEG;
    const size_t u16_elems  = feat_elems + w1_elems + w2_elems + mean_elems + idx_elems;
    const size_t need = u16_elems * sizeof(unsigned short)
                      + (size_t)NCHUNK * SLICE8;          // ~67.6 MB

    if (ws_size >= need) {
        unsigned short* featb  = (unsigned short*)d_ws;
        unsigned short* W1b    = featb + feat_elems;
        unsigned short* W2b    = W1b + w1_elems;
        unsigned short* meanb  = W2b + w2_elems;
        unsigned short* nbr16  = meanb + mean_elems;
        unsigned char*  featF8 = (unsigned char*)(nbr16 + idx_elems);

        prep_all<<<FEAT_BLKS + 256, 256, 0, stream>>>(feat, W1, W2, nbr,
                                                      featb, featF8, W1b, W2b, nbr16);
        gather_mean_fp8<<<dim3(N_NODES / GT, NCHUNK), 256, 0, stream>>>(featF8, nbr16, meanb);
        sage_gemm<<<GBLK, 512, 0, stream>>>(featb, meanb, W1b, b1, W2b, b2, out);
    } else {
        sage_naive<<<N_NODES, 256, 0, stream>>>(feat, nbr, W1, b1, W2, b2, out);
    }
}

// Round 5
// 177.335 us; speedup vs baseline: 1.0543x; 1.0218x over previous
//
#include <hip/hip_runtime.h>
#include <stdint.h>

// Problem constants (from reference)
#define N_NODES 50000
#define DEG     32
#define IN_DIM  256
#define K1      512   // 2*IN_DIM
#define HID     256
#define OUT_DIM 128

// fp8 gather tiling
#define NCHUNK  4
#define CDIM    64                          // dims per chunk (64 B fp8 per node-chunk)
#define SLICE8  ((size_t)N_NODES * CDIM)    // bytes per chunk slice (3.2 MB)
#define GT      16                          // nodes per gather block

// GEMM tiling
#define MT     32                           // nodes per tile
#define NTILES ((N_NODES + MT - 1) / MT)    // 1563
#define GBLK   512                          // persistent blocks (2/CU)
#define CSTR   520    // combined LDS row stride, bf16 elems (1040 B; row data 1024 B + 16 B pad)
#define HSTR   264    // h LDS row stride, bf16 elems (528 B)

typedef __bf16 bf16x8 __attribute__((ext_vector_type(8)));
typedef float  f32x4  __attribute__((ext_vector_type(4)));
typedef float  f32x2  __attribute__((ext_vector_type(2)));

#define PIN(x) asm volatile("" : "+v"(x))

__device__ __forceinline__ unsigned short f2bf(float f) {
    union { float f; unsigned u; } v; v.f = f;
    unsigned r = v.u + 0x7fffu + ((v.u >> 16) & 1u);  // RNE (inputs finite)
    return (unsigned short)(r >> 16);
}
__device__ __forceinline__ int clampN(int v) {
    return v < 0 ? 0 : (v >= N_NODES ? N_NODES - 1 : v);
}
__device__ __forceinline__ void async_copy16(const void* g, void* l) {
    __builtin_amdgcn_global_load_lds(
        (const __attribute__((address_space(1))) void*)g,
        (__attribute__((address_space(3))) void*)l, 16, 0, 0);
}

// ---------------- merged prep: feat->bf16 + fp8 tiled; W1/W2->bf16; nbr->u16 ----------------
#define FEAT_BLKS ((N_NODES + 7) / 8)   // 6250
__global__ __launch_bounds__(256)
void prep_all(const float* __restrict__ feat,
              const float* __restrict__ W1, const float* __restrict__ W2,
              const int*   __restrict__ nbr,
              unsigned short* __restrict__ featb,   // [N,256] bf16
              unsigned char*  __restrict__ featF8,  // [4][N][64] fp8 e4m3
              unsigned short* __restrict__ W1b, unsigned short* __restrict__ W2b,
              unsigned short* __restrict__ nbr16)
{
    const int t = threadIdx.x;
    if (blockIdx.x < FEAT_BLKS) {
        const int node = blockIdx.x * 8 + (t >> 5);  // 8 nodes/block
        const int seg  = t & 31;                     // dims seg*8 .. seg*8+7
        if (node < N_NODES) {
            const float4* src = (const float4*)(feat + (size_t)node * IN_DIM + seg * 8);
            float4 f0 = src[0], f1 = src[1];
            ushort4 o0, o1;
            o0.x = f2bf(f0.x); o0.y = f2bf(f0.y); o0.z = f2bf(f0.z); o0.w = f2bf(f0.w);
            o1.x = f2bf(f1.x); o1.y = f2bf(f1.y); o1.z = f2bf(f1.z); o1.w = f2bf(f1.w);
            unsigned short* db = featb + (size_t)node * IN_DIM + seg * 8;
            *(ushort4*)db       = o0;
            *(ushort4*)(db + 4) = o1;
            int u0 = 0, u1 = 0;
            u0 = __builtin_amdgcn_cvt_pk_fp8_f32(f0.x, f0.y, u0, false);
            u0 = __builtin_amdgcn_cvt_pk_fp8_f32(f0.z, f0.w, u0, true);
            u1 = __builtin_amdgcn_cvt_pk_fp8_f32(f1.x, f1.y, u1, false);
            u1 = __builtin_amdgcn_cvt_pk_fp8_f32(f1.z, f1.w, u1, true);
            const int c   = seg >> 3;
            const int off = (seg & 7) * 8;
            unsigned char* d8 = featF8 + (size_t)c * SLICE8 + (size_t)node * CDIM + off;
            ((int*)d8)[0] = u0;
            ((int*)d8)[1] = u1;
        }
    } else {
        const int bid = blockIdx.x - FEAT_BLKS;           // 0..255
        const int stride = 256 * 256 * 4;
        const int tid4 = (bid * 256 + t) * 4;
        for (int i = tid4; i < HID * K1; i += stride) {
            float4 f = *(const float4*)(W1 + i);
            ushort4 o; o.x = f2bf(f.x); o.y = f2bf(f.y); o.z = f2bf(f.z); o.w = f2bf(f.w);
            *(ushort4*)(W1b + i) = o;
        }
        for (int i = tid4; i < OUT_DIM * HID; i += stride) {
            float4 f = *(const float4*)(W2 + i);
            ushort4 o; o.x = f2bf(f.x); o.y = f2bf(f.y); o.z = f2bf(f.z); o.w = f2bf(f.w);
            *(ushort4*)(W2b + i) = o;
        }
        for (int i = tid4; i < N_NODES * DEG; i += stride) {
            int4 v = *(const int4*)(nbr + i);
            ushort4 o;
            o.x = (unsigned short)clampN(v.x); o.y = (unsigned short)clampN(v.y);
            o.z = (unsigned short)clampN(v.z); o.w = (unsigned short)clampN(v.w);
            *(ushort4*)(nbr16 + i) = o;
        }
    }
}

// ---------------- gather + mean: fp8 slices, round-0 proven shape ----------------
// thread = (node-slot grp 0..15, dword ln 0..15); 4 B/lane; all 32 loads issued
// before any convert (max MLP, single vmcnt drain). ~0.27 lines/cy/CU measured
// cap (random-miss throughput) — fastest of 3 shapes tried (39/44/47 µs).
__global__ __launch_bounds__(256)
void gather_mean_fp8(const unsigned char*  __restrict__ featF8,
                     const unsigned short* __restrict__ nbr16,
                     unsigned short*       __restrict__ meanb)  // [N,256] bf16
{
    __shared__ unsigned short sIdx[GT * DEG];  // 1 KB
    const int tid  = threadIdx.x;
    const int c    = blockIdx.y;
    const int base = blockIdx.x * GT;          // N % GT == 0: no tail

    if (tid < 128) {
        *(ushort4*)(sIdx + tid * 4) =
            *(const ushort4*)(nbr16 + (size_t)base * DEG + tid * 4);
    }
    __syncthreads();

    const unsigned char* slice = featF8 + (size_t)c * SLICE8;
    const int grp = tid >> 4;     // node slot 0..15
    const int ln  = tid & 15;     // dims 4*ln .. 4*ln+3 of the chunk
    const unsigned short* idxr = sIdx + grp * DEG;

    // all 32 loads issued before any use: max memory-level parallelism
    unsigned vv[DEG];
    #pragma unroll
    for (int j = 0; j < DEG; ++j) {
        int nb = idxr[j];
        vv[j] = *(const unsigned*)(slice + (size_t)nb * CDIM + ln * 4);
    }
    float s0 = 0.f, s1 = 0.f, s2 = 0.f, s3 = 0.f;
    #pragma unroll
    for (int j = 0; j < DEG; ++j) {
        f32x2 lo = __builtin_amdgcn_cvt_pk_f32_fp8(vv[j], false);
        f32x2 hi = __builtin_amdgcn_cvt_pk_f32_fp8(vv[j], true);
        s0 += lo[0]; s1 += lo[1]; s2 += hi[0]; s3 += hi[1];
    }
    const float sc = 1.0f / 32.0f;
    ushort4 o;
    o.x = f2bf(s0 * sc); o.y = f2bf(s1 * sc);
    o.z = f2bf(s2 * sc); o.w = f2bf(s3 * sc);
    const int node = base + grp;
    *(ushort4*)(meanb + (size_t)node * IN_DIM + c * CDIM + ln * 4) = o;
}

// ---------------- persistent GEMM: NO register-resident W1 (spill fix) ----------------
// Round-4 evidence: VGPR_Count=128 cap with ~190 VGPRs of pinned state -> compiler
// scratch-spilled the W1 fragments since round 0 (MfmaUtil 12%, dur 50us). Fix:
// stream W1 fragments from global (L2-resident 256 KB, shared by all blocks) inside
// the K-loop with a 4-deep statically-indexed register prefetch ring. Live set
// ~110 VGPR < 128 -> no spill. W1 re-read = 400 MB L2 total (~12us BW, overlapped).
// MFMA fragment layouts (measured, learn_hip m89/m91/m120):
//   A operand: lane holds A[m = lane&15][k = (lane>>4)*8 + j], j=0..7
//   B operand (W row-major [n][k]): lane holds W[n = lane&15][k = (lane>>4)*8 + j]
//   C/D: col(n) = lane&15, row(m) = (lane>>4)*4 + reg
__global__ __launch_bounds__(512, 2)
void sage_gemm(const unsigned short* __restrict__ featb,  // [N,256] bf16
               const unsigned short* __restrict__ meanb,  // [N,256] bf16
               const unsigned short* __restrict__ W1b,    // [256,512] bf16
               const float*          __restrict__ b1,
               const unsigned short* __restrict__ W2b,    // [128,256] bf16
               const float*          __restrict__ b2,
               float*                __restrict__ out)    // [N,128]
{
    __shared__ __align__(16) unsigned short sC[MT * CSTR];  // 33280 B
    __shared__ __align__(16) unsigned short sH[MT * HSTR];  // 16896 B (50176 total)

    const int tid  = threadIdx.x;
    const int lane = tid & 63;
    const int wave = tid >> 6;     // 0..7
    const int r    = lane & 15;
    const int q    = lane >> 4;

    // ---- one-time: W2 fragments only (32 VGPR), pinned against remat ----
    bf16x8 w2f[8];       // out-col wave*16 + r
    {
        const size_t orow = (size_t)(wave * 16 + r) * HID;
        #pragma unroll
        for (int kk = 0; kk < 8; ++kk) {
            w2f[kk] = *(const bf16x8*)(W2b + orow + kk * 32 + q * 8);
            PIN(w2f[kk]);
        }
    }
    const float bias1a = b1[wave * 32 + r];
    const float bias1b = b1[wave * 32 + 16 + r];
    const float bias2  = b2[wave * 16 + r];

    // W1 row pointers for this lane's two n-columns (nt=0/1), k-offset q*8
    const unsigned short* wrow0 = W1b + (size_t)(wave * 32 + r) * K1 + q * 8;
    const unsigned short* wrow1 = W1b + (size_t)(wave * 32 + 16 + r) * K1 + q * 8;

    // per-lane source offset within a combined row (self 512B | mean 512B)
    // HW writes lane i at lds_base + i*16 -> exactly our row layout.
    auto stage = [&](int tile) {
        const int base = tile * MT;
        #pragma unroll
        for (int j = 0; j < 4; ++j) {
            const int i = wave * 4 + j;           // row 0..31 (wave-uniform)
            int node = base + i;
            if (node >= N_NODES) node = N_NODES - 1;
            const unsigned short* g = (lane < 32)
                ? featb + (size_t)node * IN_DIM + lane * 8
                : meanb + (size_t)node * IN_DIM + (lane - 32) * 8;
            async_copy16(g, &sC[i * CSTR]);
        }
    };

    int tile = blockIdx.x;
    if (tile < NTILES) stage(tile);

    for (; tile < NTILES; tile += GBLK) {
        __syncthreads();   // compiler drains vmcnt before s_barrier: sC ready

        // ---- Phase 2: h = relu(C @ W1^T + b1); wave covers h-cols [wave*32, +32) ----
        {
            f32x4 acc[2][2];
            #pragma unroll
            for (int mt = 0; mt < 2; ++mt)
                #pragma unroll
                for (int nt = 0; nt < 2; ++nt)
                    acc[mt][nt] = (f32x4){0.f, 0.f, 0.f, 0.f};

            // 4-deep W1 prefetch ring; all indices compile-time after full unroll
            bf16x8 wP[4][2];
            #pragma unroll
            for (int p = 0; p < 4; ++p) {
                wP[p][0] = *(const bf16x8*)(wrow0 + p * 32);
                wP[p][1] = *(const bf16x8*)(wrow1 + p * 32);
            }
            #pragma unroll
            for (int kk = 0; kk < 16; ++kk) {
                bf16x8 wc0 = wP[kk & 3][0];
                bf16x8 wc1 = wP[kk & 3][1];
                if (kk < 12) {
                    wP[kk & 3][0] = *(const bf16x8*)(wrow0 + (kk + 4) * 32);
                    wP[kk & 3][1] = *(const bf16x8*)(wrow1 + (kk + 4) * 32);
                }
                bf16x8 a0 = *(const bf16x8*)(&sC[r * CSTR + kk * 32 + q * 8]);
                bf16x8 a1 = *(const bf16x8*)(&sC[(16 + r) * CSTR + kk * 32 + q * 8]);
                acc[0][0] = __builtin_amdgcn_mfma_f32_16x16x32_bf16(a0, wc0, acc[0][0], 0, 0, 0);
                acc[1][0] = __builtin_amdgcn_mfma_f32_16x16x32_bf16(a1, wc0, acc[1][0], 0, 0, 0);
                acc[0][1] = __builtin_amdgcn_mfma_f32_16x16x32_bf16(a0, wc1, acc[0][1], 0, 0, 0);
                acc[1][1] = __builtin_amdgcn_mfma_f32_16x16x32_bf16(a1, wc1, acc[1][1], 0, 0, 0);
            }
            #pragma unroll
            for (int nt = 0; nt < 2; ++nt) {
                const int n = wave * 32 + nt * 16 + r;
                const float bias = nt ? bias1b : bias1a;
                #pragma unroll
                for (int mt = 0; mt < 2; ++mt)
                    #pragma unroll
                    for (int g = 0; g < 4; ++g) {
                        const int m = mt * 16 + q * 4 + g;
                        float v = acc[mt][nt][g] + bias;
                        sH[m * HSTR + n] = f2bf(v > 0.f ? v : 0.f);
                    }
            }
        }
        __syncthreads();   // sH ready; phase-2 reads of sC complete

        // ---- prefetch next tile into sC (overlaps phase 3; drains at loop-top barrier) ----
        const int nxt = tile + GBLK;
        if (nxt < NTILES) stage(nxt);

        // ---- Phase 3: out = relu(h @ W2^T + b2); wave covers out-cols [wave*16, +16) ----
        {
            f32x4 acc3[2];
            acc3[0] = (f32x4){0.f, 0.f, 0.f, 0.f};
            acc3[1] = (f32x4){0.f, 0.f, 0.f, 0.f};
            #pragma unroll
            for (int kk = 0; kk < 8; ++kk) {
                bf16x8 h0 = *(const bf16x8*)(&sH[r * HSTR + kk * 32 + q * 8]);
                bf16x8 h1 = *(const bf16x8*)(&sH[(16 + r) * HSTR + kk * 32 + q * 8]);
                acc3[0] = __builtin_amdgcn_mfma_f32_16x16x32_bf16(h0, w2f[kk], acc3[0], 0, 0, 0);
                acc3[1] = __builtin_amdgcn_mfma_f32_16x16x32_bf16(h1, w2f[kk], acc3[1], 0, 0, 0);
            }
            const int base = tile * MT;
            const int o = wave * 16 + r;
            #pragma unroll
            for (int mt = 0; mt < 2; ++mt)
                #pragma unroll
                for (int g = 0; g < 4; ++g) {
                    const int m = mt * 16 + q * 4 + g;
                    const int node = base + m;
                    if (node < N_NODES) {
                        float v = acc3[mt][g] + bias2;
                        out[(size_t)node * OUT_DIM + o] = v > 0.f ? v : 0.f;
                    }
                }
        }
    }
}

// ---------------- naive fp32 fallback (only if ws too small) ----------------
__global__ __launch_bounds__(256)
void sage_naive(const float* __restrict__ feat, const int* __restrict__ nbr,
                const float* __restrict__ W1, const float* __restrict__ b1,
                const float* __restrict__ W2, const float* __restrict__ b2,
                float* __restrict__ out) {
    __shared__ float comb[K1];
    __shared__ float h[HID];
    const int node = blockIdx.x;
    const int t = threadIdx.x;  // 256
    comb[t] = feat[(size_t)node * IN_DIM + t];
    float acc = 0.f;
    for (int d = 0; d < DEG; ++d) {
        int nb = clampN(nbr[node * DEG + d]);
        acc += feat[(size_t)nb * IN_DIM + t];
    }
    comb[IN_DIM + t] = acc * (1.0f / 32.0f);
    __syncthreads();
    float s = b1[t];
    for (int k = 0; k < K1; ++k) s += comb[k] * W1[(size_t)t * K1 + k];
    h[t] = s > 0.f ? s : 0.f;
    __syncthreads();
    if (t < OUT_DIM) {
        float s2 = b2[t];
        for (int k = 0; k < HID; ++k) s2 += h[k] * W2[(size_t)t * HID + k];
        out[(size_t)node * OUT_DIM + t] = s2 > 0.f ? s2 : 0.f;
    }
}

extern "C" void kernel_launch(void* const* d_in, const int* in_sizes, int n_in,
                              void* d_out, int out_size, void* d_ws, size_t ws_size,
                              hipStream_t stream) {
    const float* feat = (const float*)d_in[0];
    const int*   nbr  = (const int*)d_in[1];
    const float* W1   = (const float*)d_in[2];
    const float* b1   = (const float*)d_in[3];
    const float* W2   = (const float*)d_in[4];
    const float* b2   = (const float*)d_in[5];
    float* out = (float*)d_out;

    const size_t feat_elems = (size_t)N_NODES * IN_DIM;   // 12.8M
    const size_t w1_elems   = (size_t)HID * K1;
    const size_t w2_elems   = (size_t)OUT_DIM * HID;
    const size_t mean_elems = (size_t)N_NODES * IN_DIM;
    const size_t idx_elems  = (size_t)N_NODES * DEG;
    const size_t u16_elems  = feat_elems + w1_elems + w2_elems + mean_elems + idx_elems;
    const size_t need = u16_elems * sizeof(unsigned short)
                      + (size_t)NCHUNK * SLICE8;          // ~67.6 MB

    if (ws_size >= need) {
        unsigned short* featb  = (unsigned short*)d_ws;
        unsigned short* W1b    = featb + feat_elems;
        unsigned short* W2b    = W1b + w1_elems;
        unsigned short* meanb  = W2b + w2_elems;
        unsigned short* nbr16  = meanb + mean_elems;
        unsigned char*  featF8 = (unsigned char*)(nbr16 + idx_elems);

        prep_all<<<FEAT_BLKS + 256, 256, 0, stream>>>(feat, W1, W2, nbr,
                                                      featb, featF8, W1b, W2b, nbr16);
        gather_mean_fp8<<<dim3(N_NODES / GT, NCHUNK), 256, 0, stream>>>(featF8, nbr16, meanb);
        sage_gemm<<<GBLK, 512, 0, stream>>>(featb, meanb, W1b, b1, W2b, b2, out);
    } else {
        sage_naive<<<N_NODES, 256, 0, stream>>>(feat, nbr, W1, b1, W2, b2, out);
    }
}

// Round 6
// 174.626 us; speedup vs baseline: 1.0706x; 1.0155x over previous
//
#include <hip/hip_runtime.h>
#include <stdint.h>

// Problem constants (from reference)
#define N_NODES 50000
#define DEG     32
#define IN_DIM  256
#define K1      512   // 2*IN_DIM
#define HID     256
#define OUT_DIM 128

// fp8 gather tiling
#define NCHUNK  4
#define CDIM    64                          // dims per chunk (64 B fp8 per node-chunk)
#define SLICE8  ((size_t)N_NODES * CDIM)    // bytes per chunk slice (3.2 MB)
#define GT      16                          // nodes per gather block

// GEMM tiling
#define MT     32                           // nodes per tile
#define NTILES ((N_NODES + MT - 1) / MT)    // 1563
#define GBLK   256                          // persistent blocks (1/CU; 256-VGPR waves)
#define CSTR   520    // combined LDS row stride, bf16 elems (1040 B)
#define HSTR   264    // h LDS row stride, bf16 elems (528 B)

typedef __bf16 bf16x8 __attribute__((ext_vector_type(8)));
typedef float  f32x4  __attribute__((ext_vector_type(4)));
typedef float  f32x2  __attribute__((ext_vector_type(2)));

#define PIN(x) asm volatile("" : "+v"(x))

__device__ __forceinline__ unsigned short f2bf(float f) {
    union { float f; unsigned u; } v; v.f = f;
    unsigned r = v.u + 0x7fffu + ((v.u >> 16) & 1u);  // RNE (inputs finite)
    return (unsigned short)(r >> 16);
}
__device__ __forceinline__ int clampN(int v) {
    return v < 0 ? 0 : (v >= N_NODES ? N_NODES - 1 : v);
}
__device__ __forceinline__ void async_copy16(const void* g, void* l) {
    __builtin_amdgcn_global_load_lds(
        (const __attribute__((address_space(1))) void*)g,
        (__attribute__((address_space(3))) void*)l, 16, 0, 0);
}

// ---------------- merged prep: feat->bf16 + fp8 tiled; W1/W2->bf16; nbr->u16 ----------------
#define FEAT_BLKS ((N_NODES + 7) / 8)   // 6250
__global__ __launch_bounds__(256)
void prep_all(const float* __restrict__ feat,
              const float* __restrict__ W1, const float* __restrict__ W2,
              const int*   __restrict__ nbr,
              unsigned short* __restrict__ featb,   // [N,256] bf16
              unsigned char*  __restrict__ featF8,  // [4][N][64] fp8 e4m3
              unsigned short* __restrict__ W1b, unsigned short* __restrict__ W2b,
              unsigned short* __restrict__ nbr16)
{
    const int t = threadIdx.x;
    if (blockIdx.x < FEAT_BLKS) {
        const int node = blockIdx.x * 8 + (t >> 5);  // 8 nodes/block
        const int seg  = t & 31;                     // dims seg*8 .. seg*8+7
        if (node < N_NODES) {
            const float4* src = (const float4*)(feat + (size_t)node * IN_DIM + seg * 8);
            float4 f0 = src[0], f1 = src[1];
            ushort4 o0, o1;
            o0.x = f2bf(f0.x); o0.y = f2bf(f0.y); o0.z = f2bf(f0.z); o0.w = f2bf(f0.w);
            o1.x = f2bf(f1.x); o1.y = f2bf(f1.y); o1.z = f2bf(f1.z); o1.w = f2bf(f1.w);
            unsigned short* db = featb + (size_t)node * IN_DIM + seg * 8;
            *(ushort4*)db       = o0;
            *(ushort4*)(db + 4) = o1;
            int u0 = 0, u1 = 0;
            u0 = __builtin_amdgcn_cvt_pk_fp8_f32(f0.x, f0.y, u0, false);
            u0 = __builtin_amdgcn_cvt_pk_fp8_f32(f0.z, f0.w, u0, true);
            u1 = __builtin_amdgcn_cvt_pk_fp8_f32(f1.x, f1.y, u1, false);
            u1 = __builtin_amdgcn_cvt_pk_fp8_f32(f1.z, f1.w, u1, true);
            const int c   = seg >> 3;
            const int off = (seg & 7) * 8;
            unsigned char* d8 = featF8 + (size_t)c * SLICE8 + (size_t)node * CDIM + off;
            ((int*)d8)[0] = u0;
            ((int*)d8)[1] = u1;
        }
    } else {
        const int bid = blockIdx.x - FEAT_BLKS;           // 0..255
        const int stride = 256 * 256 * 4;
        const int tid4 = (bid * 256 + t) * 4;
        for (int i = tid4; i < HID * K1; i += stride) {
            float4 f = *(const float4*)(W1 + i);
            ushort4 o; o.x = f2bf(f.x); o.y = f2bf(f.y); o.z = f2bf(f.z); o.w = f2bf(f.w);
            *(ushort4*)(W1b + i) = o;
        }
        for (int i = tid4; i < OUT_DIM * HID; i += stride) {
            float4 f = *(const float4*)(W2 + i);
            ushort4 o; o.x = f2bf(f.x); o.y = f2bf(f.y); o.z = f2bf(f.z); o.w = f2bf(f.w);
            *(ushort4*)(W2b + i) = o;
        }
        for (int i = tid4; i < N_NODES * DEG; i += stride) {
            int4 v = *(const int4*)(nbr + i);
            ushort4 o;
            o.x = (unsigned short)clampN(v.x); o.y = (unsigned short)clampN(v.y);
            o.z = (unsigned short)clampN(v.z); o.w = (unsigned short)clampN(v.w);
            *(ushort4*)(nbr16 + i) = o;
        }
    }
}

// ---------------- gather + mean: fp8 slices, round-0 proven shape ----------------
// thread = (node-slot grp 0..15, dword ln 0..15); 4 B/lane; all 32 loads issued
// before any convert (max MLP, single vmcnt drain). ~0.27 lines/cy/CU measured
// cap (random-line throughput) — fastest of 3 shapes tried (39/44/47 µs).
__global__ __launch_bounds__(256)
void gather_mean_fp8(const unsigned char*  __restrict__ featF8,
                     const unsigned short* __restrict__ nbr16,
                     unsigned short*       __restrict__ meanb)  // [N,256] bf16
{
    __shared__ unsigned short sIdx[GT * DEG];  // 1 KB
    const int tid  = threadIdx.x;
    const int c    = blockIdx.y;
    const int base = blockIdx.x * GT;          // N % GT == 0: no tail

    if (tid < 128) {
        *(ushort4*)(sIdx + tid * 4) =
            *(const ushort4*)(nbr16 + (size_t)base * DEG + tid * 4);
    }
    __syncthreads();

    const unsigned char* slice = featF8 + (size_t)c * SLICE8;
    const int grp = tid >> 4;     // node slot 0..15
    const int ln  = tid & 15;     // dims 4*ln .. 4*ln+3 of the chunk
    const unsigned short* idxr = sIdx + grp * DEG;

    // all 32 loads issued before any use: max memory-level parallelism
    unsigned vv[DEG];
    #pragma unroll
    for (int j = 0; j < DEG; ++j) {
        int nb = idxr[j];
        vv[j] = *(const unsigned*)(slice + (size_t)nb * CDIM + ln * 4);
    }
    float s0 = 0.f, s1 = 0.f, s2 = 0.f, s3 = 0.f;
    #pragma unroll
    for (int j = 0; j < DEG; ++j) {
        f32x2 lo = __builtin_amdgcn_cvt_pk_f32_fp8(vv[j], false);
        f32x2 hi = __builtin_amdgcn_cvt_pk_f32_fp8(vv[j], true);
        s0 += lo[0]; s1 += lo[1]; s2 += hi[0]; s3 += hi[1];
    }
    const float sc = 1.0f / 32.0f;
    ushort4 o;
    o.x = f2bf(s0 * sc); o.y = f2bf(s1 * sc);
    o.z = f2bf(s2 * sc); o.w = f2bf(s3 * sc);
    const int node = base + grp;
    *(ushort4*)(meanb + (size_t)node * IN_DIM + c * CDIM + ln * 4) = o;
}

// ---------------- persistent GEMM: 256-VGPR waves, truly-resident W fragments ----------------
// Round-4/5 post-mortem: __launch_bounds__(512,2) capped VGPR at 128 (= 512/4 waves),
// but the wanted live set is ~230 (w1f 128 + w2f 32 + acc 24 + frags/addr). The
// allocator spilled W fragments to scratch every round since round 0 -> MfmaUtil 12-14%,
// gemm 44-50us. Fix: __launch_bounds__(512,1) -> 256-VGPR budget, 2 waves/SIMD,
// 1 block/CU (GBLK=256, ~6 tiles each). K-loop is then pure LDS+MFMA, W1 read once
// per block (128 MB L2 total). VERIFY next round: VGPR_Count must read ~200-256.
// MFMA fragment layouts (measured, learn_hip m89/m91/m120):
//   A operand: lane holds A[m = lane&15][k = (lane>>4)*8 + j], j=0..7
//   B operand (W row-major [n][k]): lane holds W[n = lane&15][k = (lane>>4)*8 + j]
//   C/D: col(n) = lane&15, row(m) = (lane>>4)*4 + reg
__global__ __launch_bounds__(512, 1)
void sage_gemm(const unsigned short* __restrict__ featb,  // [N,256] bf16
               const unsigned short* __restrict__ meanb,  // [N,256] bf16
               const unsigned short* __restrict__ W1b,    // [256,512] bf16
               const float*          __restrict__ b1,
               const unsigned short* __restrict__ W2b,    // [128,256] bf16
               const float*          __restrict__ b2,
               float*                __restrict__ out)    // [N,128]
{
    __shared__ __align__(16) unsigned short sC[MT * CSTR];  // 33280 B
    __shared__ __align__(16) unsigned short sH[MT * HSTR];  // 16896 B (50176 total)

    const int tid  = threadIdx.x;
    const int lane = tid & 63;
    const int wave = tid >> 6;     // 0..7
    const int r    = lane & 15;
    const int q    = lane >> 4;

    // ---- one-time: W fragments into registers, pinned against remat ----
    bf16x8 w1f[2][16];   // h-cols wave*32 + nt*16 + r   (128 VGPR)
    #pragma unroll
    for (int nt = 0; nt < 2; ++nt) {
        const size_t nrow = (size_t)(wave * 32 + nt * 16 + r) * K1;
        #pragma unroll
        for (int kk = 0; kk < 16; ++kk) {
            w1f[nt][kk] = *(const bf16x8*)(W1b + nrow + kk * 32 + q * 8);
            PIN(w1f[nt][kk]);
        }
    }
    bf16x8 w2f[8];       // out-col wave*16 + r          (32 VGPR)
    {
        const size_t orow = (size_t)(wave * 16 + r) * HID;
        #pragma unroll
        for (int kk = 0; kk < 8; ++kk) {
            w2f[kk] = *(const bf16x8*)(W2b + orow + kk * 32 + q * 8);
            PIN(w2f[kk]);
        }
    }
    const float bias1a = b1[wave * 32 + r];
    const float bias1b = b1[wave * 32 + 16 + r];
    const float bias2  = b2[wave * 16 + r];

    // per-lane source offset within a combined row (self 512B | mean 512B)
    // HW writes lane i at lds_base + i*16 -> exactly our row layout.
    auto stage = [&](int tile) {
        const int base = tile * MT;
        #pragma unroll
        for (int j = 0; j < 4; ++j) {
            const int i = wave * 4 + j;           // row 0..31 (wave-uniform)
            int node = base + i;
            if (node >= N_NODES) node = N_NODES - 1;
            const unsigned short* g = (lane < 32)
                ? featb + (size_t)node * IN_DIM + lane * 8
                : meanb + (size_t)node * IN_DIM + (lane - 32) * 8;
            async_copy16(g, &sC[i * CSTR]);
        }
    };

    int tile = blockIdx.x;
    if (tile < NTILES) stage(tile);

    for (; tile < NTILES; tile += GBLK) {
        __syncthreads();   // compiler drains vmcnt before s_barrier: sC ready

        // ---- Phase 2: h = relu(C @ W1^T + b1); wave covers h-cols [wave*32, +32) ----
        {
            f32x4 acc[2][2];
            #pragma unroll
            for (int mt = 0; mt < 2; ++mt)
                #pragma unroll
                for (int nt = 0; nt < 2; ++nt)
                    acc[mt][nt] = (f32x4){0.f, 0.f, 0.f, 0.f};

            #pragma unroll
            for (int kk = 0; kk < 16; ++kk) {
                bf16x8 a0 = *(const bf16x8*)(&sC[r * CSTR + kk * 32 + q * 8]);
                bf16x8 a1 = *(const bf16x8*)(&sC[(16 + r) * CSTR + kk * 32 + q * 8]);
                acc[0][0] = __builtin_amdgcn_mfma_f32_16x16x32_bf16(a0, w1f[0][kk], acc[0][0], 0, 0, 0);
                acc[1][0] = __builtin_amdgcn_mfma_f32_16x16x32_bf16(a1, w1f[0][kk], acc[1][0], 0, 0, 0);
                acc[0][1] = __builtin_amdgcn_mfma_f32_16x16x32_bf16(a0, w1f[1][kk], acc[0][1], 0, 0, 0);
                acc[1][1] = __builtin_amdgcn_mfma_f32_16x16x32_bf16(a1, w1f[1][kk], acc[1][1], 0, 0, 0);
            }
            #pragma unroll
            for (int nt = 0; nt < 2; ++nt) {
                const int n = wave * 32 + nt * 16 + r;
                const float bias = nt ? bias1b : bias1a;
                #pragma unroll
                for (int mt = 0; mt < 2; ++mt)
                    #pragma unroll
                    for (int g = 0; g < 4; ++g) {
                        const int m = mt * 16 + q * 4 + g;
                        float v = acc[mt][nt][g] + bias;
                        sH[m * HSTR + n] = f2bf(v > 0.f ? v : 0.f);
                    }
            }
        }
        __syncthreads();   // sH ready; phase-2 reads of sC complete

        // ---- prefetch next tile into sC (overlaps phase 3; drains at loop-top barrier) ----
        const int nxt = tile + GBLK;
        if (nxt < NTILES) stage(nxt);

        // ---- Phase 3: out = relu(h @ W2^T + b2); wave covers out-cols [wave*16, +16) ----
        {
            f32x4 acc3[2];
            acc3[0] = (f32x4){0.f, 0.f, 0.f, 0.f};
            acc3[1] = (f32x4){0.f, 0.f, 0.f, 0.f};
            #pragma unroll
            for (int kk = 0; kk < 8; ++kk) {
                bf16x8 h0 = *(const bf16x8*)(&sH[r * HSTR + kk * 32 + q * 8]);
                bf16x8 h1 = *(const bf16x8*)(&sH[(16 + r) * HSTR + kk * 32 + q * 8]);
                acc3[0] = __builtin_amdgcn_mfma_f32_16x16x32_bf16(h0, w2f[kk], acc3[0], 0, 0, 0);
                acc3[1] = __builtin_amdgcn_mfma_f32_16x16x32_bf16(h1, w2f[kk], acc3[1], 0, 0, 0);
            }
            const int base = tile * MT;
            const int o = wave * 16 + r;
            #pragma unroll
            for (int mt = 0; mt < 2; ++mt)
                #pragma unroll
                for (int g = 0; g < 4; ++g) {
                    const int m = mt * 16 + q * 4 + g;
                    const int node = base + m;
                    if (node < N_NODES) {
                        float v = acc3[mt][g] + bias2;
                        out[(size_t)node * OUT_DIM + o] = v > 0.f ? v : 0.f;
                    }
                }
        }
    }
}

// ---------------- naive fp32 fallback (only if ws too small) ----------------
__global__ __launch_bounds__(256)
void sage_naive(const float* __restrict__ feat, const int* __restrict__ nbr,
                const float* __restrict__ W1, const float* __restrict__ b1,
                const float* __restrict__ W2, const float* __restrict__ b2,
                float* __restrict__ out) {
    __shared__ float comb[K1];
    __shared__ float h[HID];
    const int node = blockIdx.x;
    const int t = threadIdx.x;  // 256
    comb[t] = feat[(size_t)node * IN_DIM + t];
    float acc = 0.f;
    for (int d = 0; d < DEG; ++d) {
        int nb = clampN(nbr[node * DEG + d]);
        acc += feat[(size_t)nb * IN_DIM + t];
    }
    comb[IN_DIM + t] = acc * (1.0f / 32.0f);
    __syncthreads();
    float s = b1[t];
    for (int k = 0; k < K1; ++k) s += comb[k] * W1[(size_t)t * K1 + k];
    h[t] = s > 0.f ? s : 0.f;
    __syncthreads();
    if (t < OUT_DIM) {
        float s2 = b2[t];
        for (int k = 0; k < HID; ++k) s2 += h[k] * W2[(size_t)t * HID + k];
        out[(size_t)node * OUT_DIM + t] = s2 > 0.f ? s2 : 0.f;
    }
}

extern "C" void kernel_launch(void* const* d_in, const int* in_sizes, int n_in,
                              void* d_out, int out_size, void* d_ws, size_t ws_size,
                              hipStream_t stream) {
    const float* feat = (const float*)d_in[0];
    const int*   nbr  = (const int*)d_in[1];
    const float* W1   = (const float*)d_in[2];
    const float* b1   = (const float*)d_in[3];
    const float* W2   = (const float*)d_in[4];
    const float* b2   = (const float*)d_in[5];
    float* out = (float*)d_out;

    const size_t feat_elems = (size_t)N_NODES * IN_DIM;   // 12.8M
    const size_t w1_elems   = (size_t)HID * K1;
    const size_t w2_elems   = (size_t)OUT_DIM * HID;
    const size_t mean_elems = (size_t)N_NODES * IN_DIM;
    const size_t idx_elems  = (size_t)N_NODES * DEG;
    const size_t u16_elems  = feat_elems + w1_elems + w2_elems + mean_elems + idx_elems;
    const size_t need = u16_elems * sizeof(unsigned short)
                      + (size_t)NCHUNK * SLICE8;          // ~67.6 MB

    if (ws_size >= need) {
        unsigned short* featb  = (unsigned short*)d_ws;
        unsigned short* W1b    = featb + feat_elems;
        unsigned short* W2b    = W1b + w1_elems;
        unsigned short* meanb  = W2b + w2_elems;
        unsigned short* nbr16  = meanb + mean_elems;
        unsigned char*  featF8 = (unsigned char*)(nbr16 + idx_elems);

        prep_all<<<FEAT_BLKS + 256, 256, 0, stream>>>(feat, W1, W2, nbr,
                                                      featb, featF8, W1b, W2b, nbr16);
        gather_mean_fp8<<<dim3(N_NODES / GT, NCHUNK), 256, 0, stream>>>(featF8, nbr16, meanb);
        sage_gemm<<<GBLK, 512, 0, stream>>>(featb, meanb, W1b, b1, W2b, b2, out);
    } else {
        sage_naive<<<N_NODES, 256, 0, stream>>>(feat, nbr, W1, b1, W2, b2, out);
    }
}